// Round 3
// baseline (159.390 us; speedup 1.0000x reference)
//
#include <hip/hip_runtime.h>

// YOLO loss, S=14, B=2, C=20, N_EL=30, batch=4096, 16 boxes/row.
// Channel-decomposed, stream-oriented:
//   1) memset winner[total+1] = -1; encode: atomicMax packed (k<<8)|hot per cell
//      (max box index == last-wins scatter semantics).
//   2) stream kernel: the whole 96MB pred as coalesced float4, branchless
//      per-channel terms (noobj conf ch4/9, class ch10..29) using winner[].
//   3) obj kernel: one thread per (batch,box); the winning box computes
//      contain + 5*loc from its cell's first 10 channels (L3-warm).
//   4) final 1-block reduce over block partials.

#define SGRID 14
#define CELLS 196
#define NEL 30
#define NBOX 16
#define PRED_PER_BATCH 5880
#define STREAM_ITERS 12
#define STREAM_TPB 256
#define STREAM_CHUNK (STREAM_ITERS * STREAM_TPB)   // 3072 float4 per block

__device__ __forceinline__ void block_reduce_store(float v, float* slot) {
    #pragma unroll
    for (int off = 32; off > 0; off >>= 1)
        v += __shfl_down(v, off, 64);
    __shared__ float w4[4];
    int tid = threadIdx.x;
    if ((tid & 63) == 0) w4[tid >> 6] = v;
    __syncthreads();
    if (tid == 0) *slot = w4[0] + w4[1] + w4[2] + w4[3];
}

__global__ __launch_bounds__(256) void encode_kernel(
    const float4* __restrict__ boxes, const int* __restrict__ classes,
    int* __restrict__ winner, int nbb)
{
    int t = blockIdx.x * 256 + threadIdx.x;
    if (t >= nbb) return;
    int b = t >> 4, k = t & 15;
    float4 bx = boxes[t];
    const float cellw = (float)(1.0 / 14.0);   // match jnp: divide by float32(1/14)
    float cx = (bx.x + bx.z) * 0.5f, cy = (bx.y + bx.w) * 0.5f;
    float fx = cx / cellw, fy = cy / cellw;
    float fi = fminf(fmaxf(ceilf(fx) - 1.0f, 0.0f), 13.0f);
    float fj = fminf(fmaxf(ceilf(fy) - 1.0f, 0.0f), 13.0f);
    int cell = (int)fj * SGRID + (int)fi;
    int hot = 9 + classes[t];                  // faithful off-by-one (cls 0 -> ch9)
    atomicMax(&winner[b * CELLS + cell], (k << 8) | hot);
}

__global__ __launch_bounds__(256) void stream_kernel(
    const float4* __restrict__ pred4, const int* __restrict__ winner,
    float* __restrict__ partials, int nvec)
{
    int base = blockIdx.x * STREAM_CHUNK + threadIdx.x;
    float loss = 0.0f;
    #pragma unroll
    for (int i = 0; i < STREAM_ITERS; ++i) {
        int e = base + i * STREAM_TPB;
        if (e < nvec) {
            float4 v = pred4[e];
            int g = e * 4;                         // global float index
            int cell = (int)((unsigned)g / 30u);   // magic-mul div
            int c0 = g - cell * 30;
            int m0 = winner[cell];
            int m1 = winner[cell + 1];             // winner has a -1 sentinel at [total]
            float pv[4] = {v.x, v.y, v.z, v.w};
            #pragma unroll
            for (int j = 0; j < 4; ++j) {
                int cj = c0 + j;
                int cc = (cj >= 30) ? cj - 30 : cj;
                int m  = (cj >= 30) ? m1 : m0;
                bool isconf = (cc == 4) | (cc == 9);
                float wgt = isconf ? ((m < 0) ? 0.5f : 0.0f)
                                   : ((cc >= 10) ? ((m >= 0) ? 1.0f : 0.0f) : 0.0f);
                // one-hot target: only hits when cc==hot (>=10); m<0 -> m&0xFF=255, no match
                float tt = (cc == (m & 0xFF)) ? 1.0f : 0.0f;
                float d = pv[j] - tt;
                loss += wgt * d * d;
            }
        }
    }
    block_reduce_store(loss, &partials[blockIdx.x]);
}

__global__ __launch_bounds__(256) void obj_kernel(
    const float* __restrict__ pred, const float4* __restrict__ boxes,
    const int* __restrict__ winner, float* __restrict__ partials, int nbb)
{
    int t = blockIdx.x * 256 + threadIdx.x;
    float loss = 0.0f;
    if (t < nbb) {
        int b = t >> 4, k = t & 15;
        float4 bx = boxes[t];
        const float cellw = (float)(1.0 / 14.0);
        float w = bx.z - bx.x, h = bx.w - bx.y;
        float cx = (bx.x + bx.z) * 0.5f, cy = (bx.y + bx.w) * 0.5f;
        float fx = cx / cellw, fy = cy / cellw;
        float fi = fminf(fmaxf(ceilf(fx) - 1.0f, 0.0f), 13.0f);
        float fj = fminf(fmaxf(ceilf(fy) - 1.0f, 0.0f), 13.0f);
        float dx = fx - fi, dy = fy - fj;
        int idx = b * CELLS + (int)fj * SGRID + (int)fi;
        int wv = winner[idx];
        if ((wv >> 8) == k) {                      // this box won its cell
            const float* p = pred + (size_t)idx * NEL;
            float a[10];
            #pragma unroll
            for (int j = 0; j < 5; ++j) {          // 8B-aligned float2 loads
                float2 v = *(const float2*)(p + 2 * j);
                a[2 * j] = v.x;  a[2 * j + 1] = v.y;
            }
            // corner-format "IoU" of (dx,dy,w,h) rows verbatim (per reference)
            float area_t = (w - dx) * (h - dy);
            float iou[2];
            #pragma unroll
            for (int i = 0; i < 2; ++i) {
                const float* q = a + i * 5;
                float ltx = fmaxf(q[0], dx), lty = fmaxf(q[1], dy);
                float rbx = fminf(q[2], w),  rby = fminf(q[3], h);
                float wi = fmaxf(rbx - ltx, 0.0f);
                float hi = fmaxf(rby - lty, 0.0f);
                float inter  = wi * hi;
                float area_a = (q[2] - q[0]) * (q[3] - q[1]);
                float uni    = area_a + area_t - inter;
                iou[i] = inter / ((uni == 0.0f) ? 1.0f : uni);
            }
            int r = (iou[1] > iou[0]) ? 1 : 0;     // argmax tie -> 0
            const float* q = a + r * 5;
            float dc = q[4] - 1.0f;                // contain
            loss += dc * dc;
            float lx = q[0] - dx, ly = q[1] - dy;  // 5 * loc
            float lw = sqrtf(q[2]) - sqrtf(w);
            float lh = sqrtf(q[3]) - sqrtf(h);
            loss += 5.0f * (lx * lx + ly * ly + lw * lw + lh * lh);
        }
    }
    block_reduce_store(loss, &partials[blockIdx.x]);
}

__global__ __launch_bounds__(256) void final_reduce_kernel(
    const float* __restrict__ partials, float* __restrict__ out, int n)
{
    float s = 0.0f;
    for (int i = threadIdx.x; i < n; i += 256) s += partials[i];
    #pragma unroll
    for (int off = 32; off > 0; off >>= 1)
        s += __shfl_down(s, off, 64);
    __shared__ float w4[4];
    if ((threadIdx.x & 63) == 0) w4[threadIdx.x >> 6] = s;
    __syncthreads();
    if (threadIdx.x == 0) out[0] = w4[0] + w4[1] + w4[2] + w4[3];
}

extern "C" void kernel_launch(void* const* d_in, const int* in_sizes, int n_in,
                              void* d_out, int out_size, void* d_ws, size_t ws_size,
                              hipStream_t stream) {
    const float* pred    = (const float*)d_in[0];
    const float* boxes   = (const float*)d_in[1];
    const int*   classes = (const int*)d_in[2];
    float* out = (float*)d_out;

    const int batch = in_sizes[0] / PRED_PER_BATCH;    // 4096
    const int total = batch * CELLS;                   // 802816 cells
    const int nbb   = batch * NBOX;                    // 65536
    const int nvec  = total * NEL / 4;                 // 6021120 float4

    const int sblocks = (nvec + STREAM_CHUNK - 1) / STREAM_CHUNK;   // 1960 (exact)
    const int oblocks = (nbb + 255) / 256;                          // 256
    const int nparts  = sblocks + oblocks;

    // ws layout: winner int[total+1] | partials float[nparts]
    int*   winner   = (int*)d_ws;
    float* partials = (float*)((char*)d_ws + (size_t)(total + 1) * sizeof(int));

    hipMemsetAsync(winner, 0xFF, (size_t)(total + 1) * sizeof(int), stream);
    encode_kernel<<<dim3((nbb + 255) / 256), dim3(256), 0, stream>>>(
        (const float4*)boxes, classes, winner, nbb);
    stream_kernel<<<dim3(sblocks), dim3(256), 0, stream>>>(
        (const float4*)pred, winner, partials, nvec);
    obj_kernel<<<dim3(oblocks), dim3(256), 0, stream>>>(
        pred, (const float4*)boxes, winner, partials + sblocks, nbb);
    final_reduce_kernel<<<dim3(1), dim3(256), 0, stream>>>(partials, out, nparts);
}

// Round 4
// 146.761 us; speedup vs baseline: 1.0860x; 1.0860x over previous
//
#include <hip/hip_runtime.h>

// YOLO loss, S=14, B=2, C=20, N_EL=30, batch=4096, 16 boxes/row.
// Fully fused, 2 dispatches:
//   1) fused kernel, one block per 3072-float4 stream chunk:
//      a) rebuild winner map for the <=4 batch rows overlapping the chunk in
//         LDS (atomicMax of (k<<8)|hot == last-wins scatter semantics);
//      b) stream the chunk as unconditional coalesced float4, branchless
//         per-channel terms (noobj conf ch4/9, class ch10..29) from LDS winner;
//      c) contain + 5*loc for rows STARTING in this chunk (exact dedupe);
//      d) block shfl-reduce -> one plain partial store.
//   2) 1-block reduce of the 1960 partials -> out[0] (plain store, no memset).

#define SGRID 14
#define CELLS 196
#define NEL 30
#define NBOX 16
#define PRED_PER_BATCH 5880
#define VEC_PER_ROW 1470               // 5880/4
#define STREAM_ITERS 12
#define STREAM_TPB 256
#define STREAM_CHUNK (STREAM_ITERS * STREAM_TPB)   // 3072 float4
#define WIN_TILE (4 * CELLS + 4)       // 4 rows + straddle pad

__global__ __launch_bounds__(256) void yolo_fused_kernel(
    const float4* __restrict__ pred4,
    const float4* __restrict__ boxes,
    const int*    __restrict__ classes,
    float* __restrict__ partials,
    int nvec, int nrows)
{
    __shared__ int   s_win[WIN_TILE];
    __shared__ float s_w4[4];

    const int tid = threadIdx.x;
    const int v0  = blockIdx.x * STREAM_CHUNK;
    const int r0  = v0 / VEC_PER_ROW;          // first batch row overlapping chunk
    const float cellw = (float)(1.0 / 14.0);   // match jnp: divide by float32(1/14)

    // ---- a) clear + build winner tile for rows r0..r0+3 ----
    #pragma unroll
    for (int i = 0; i < (WIN_TILE + STREAM_TPB - 1) / STREAM_TPB; ++i) {
        int idx = tid + i * STREAM_TPB;
        if (idx < WIN_TILE) s_win[idx] = -1;
    }
    __syncthreads();
    if (tid < 4 * NBOX) {
        int rr = tid >> 4, row = r0 + rr, k = tid & 15;
        if (row < nrows) {
            float4 bx = boxes[row * NBOX + k];
            float cx = (bx.x + bx.z) * 0.5f, cy = (bx.y + bx.w) * 0.5f;
            float fx = cx / cellw, fy = cy / cellw;
            float fi = fminf(fmaxf(ceilf(fx) - 1.0f, 0.0f), 13.0f);
            float fj = fminf(fmaxf(ceilf(fy) - 1.0f, 0.0f), 13.0f);
            int cell = (int)fj * SGRID + (int)fi;
            int hot  = 9 + classes[row * NBOX + k];  // faithful off-by-one
            atomicMax(&s_win[rr * CELLS + cell], (k << 8) | hot);
        }
    }
    __syncthreads();

    // ---- b) stream chunk: 12 unconditional float4 (uniform tail branch) ----
    const int cellbase = r0 * CELLS;
    float loss = 0.0f;
    const bool full = (v0 + STREAM_CHUNK) <= nvec;
    #pragma unroll
    for (int i = 0; i < STREAM_ITERS; ++i) {
        int e = v0 + tid + i * STREAM_TPB;
        if (full || e < nvec) {
            float4 v = pred4[e];
            int g    = e * 4;
            int cell = (int)((unsigned)g / 30u);
            int c0   = g - cell * 30;
            int lc   = cell - cellbase;
            int m0 = s_win[lc];
            int m1 = s_win[lc + 1];
            float pv[4] = {v.x, v.y, v.z, v.w};
            #pragma unroll
            for (int j = 0; j < 4; ++j) {
                int cj = c0 + j;
                bool str = cj >= 30;
                int cc = str ? cj - 30 : cj;
                int m  = str ? m1 : m0;
                bool isconf = (cc == 4) | (cc == 9);
                float wgt = isconf ? ((m < 0) ? 0.5f : 0.0f)
                                   : ((cc >= 10) ? ((m >= 0) ? 1.0f : 0.0f) : 0.0f);
                float tt = (cc == (m & 0xFF)) ? 1.0f : 0.0f;  // m<0 -> 255, no hit
                float d = pv[j] - tt;
                loss += wgt * d * d;
            }
        }
    }

    // ---- c) obj loss for rows starting in this chunk (dedupe across blocks) ----
    if (tid < 4 * NBOX) {
        int rr = tid >> 4, row = r0 + rr, k = tid & 15;
        int rstart = row * VEC_PER_ROW;
        if (row < nrows && rstart >= v0 && rstart < v0 + STREAM_CHUNK) {
            float4 bx = boxes[row * NBOX + k];
            float w = bx.z - bx.x, h = bx.w - bx.y;
            float cx = (bx.x + bx.z) * 0.5f, cy = (bx.y + bx.w) * 0.5f;
            float fx = cx / cellw, fy = cy / cellw;
            float fi = fminf(fmaxf(ceilf(fx) - 1.0f, 0.0f), 13.0f);
            float fj = fminf(fmaxf(ceilf(fy) - 1.0f, 0.0f), 13.0f);
            float dx = fx - fi, dy = fy - fj;
            int cell = (int)fj * SGRID + (int)fi;
            int wv = s_win[rr * CELLS + cell];
            if ((wv >> 8) == k) {                  // this box won its cell
                const float* p = (const float*)pred4 + (size_t)(row * CELLS + cell) * NEL;
                float a[10];
                #pragma unroll
                for (int j = 0; j < 5; ++j) {      // 8B-aligned float2 loads
                    float2 v = *(const float2*)(p + 2 * j);
                    a[2 * j] = v.x;  a[2 * j + 1] = v.y;
                }
                // corner-format "IoU" of (dx,dy,w,h) rows verbatim (per reference)
                float area_t = (w - dx) * (h - dy);
                float iou[2];
                #pragma unroll
                for (int i = 0; i < 2; ++i) {
                    const float* q = a + i * 5;
                    float ltx = fmaxf(q[0], dx), lty = fmaxf(q[1], dy);
                    float rbx = fminf(q[2], w),  rby = fminf(q[3], h);
                    float wi = fmaxf(rbx - ltx, 0.0f);
                    float hi = fmaxf(rby - lty, 0.0f);
                    float inter  = wi * hi;
                    float area_a = (q[2] - q[0]) * (q[3] - q[1]);
                    float uni    = area_a + area_t - inter;
                    iou[i] = inter / ((uni == 0.0f) ? 1.0f : uni);
                }
                int r = (iou[1] > iou[0]) ? 1 : 0; // argmax tie -> 0
                const float* q = a + r * 5;
                float dc = q[4] - 1.0f;            // contain
                loss += dc * dc;
                float lx = q[0] - dx, ly = q[1] - dy;  // 5 * loc
                float lw = sqrtf(q[2]) - sqrtf(w);
                float lh = sqrtf(q[3]) - sqrtf(h);
                loss += 5.0f * (lx * lx + ly * ly + lw * lw + lh * lh);
            }
        }
    }

    // ---- d) block reduce -> plain partial store ----
    #pragma unroll
    for (int off = 32; off > 0; off >>= 1)
        loss += __shfl_down(loss, off, 64);
    if ((tid & 63) == 0) s_w4[tid >> 6] = loss;
    __syncthreads();
    if (tid == 0)
        partials[blockIdx.x] = s_w4[0] + s_w4[1] + s_w4[2] + s_w4[3];
}

__global__ __launch_bounds__(256) void final_reduce_kernel(
    const float* __restrict__ partials, float* __restrict__ out, int n)
{
    float s = 0.0f;
    for (int i = threadIdx.x; i < n; i += 256) s += partials[i];
    #pragma unroll
    for (int off = 32; off > 0; off >>= 1)
        s += __shfl_down(s, off, 64);
    __shared__ float w4[4];
    if ((threadIdx.x & 63) == 0) w4[threadIdx.x >> 6] = s;
    __syncthreads();
    if (threadIdx.x == 0) out[0] = w4[0] + w4[1] + w4[2] + w4[3];
}

extern "C" void kernel_launch(void* const* d_in, const int* in_sizes, int n_in,
                              void* d_out, int out_size, void* d_ws, size_t ws_size,
                              hipStream_t stream) {
    const float* pred    = (const float*)d_in[0];
    const float* boxes   = (const float*)d_in[1];
    const int*   classes = (const int*)d_in[2];
    float* out = (float*)d_out;

    const int nrows = in_sizes[0] / PRED_PER_BATCH;        // 4096
    const int nvec  = nrows * PRED_PER_BATCH / 4;          // 6021120 float4
    const int sblocks = (nvec + STREAM_CHUNK - 1) / STREAM_CHUNK;  // 1960 (exact)

    float* partials = (float*)d_ws;

    yolo_fused_kernel<<<dim3(sblocks), dim3(STREAM_TPB), 0, stream>>>(
        (const float4*)pred, (const float4*)boxes, classes, partials, nvec, nrows);
    final_reduce_kernel<<<dim3(1), dim3(256), 0, stream>>>(partials, out, sblocks);
}